// Round 2
// baseline (5192.705 us; speedup 1.0000x reference)
//
#include <hip/hip_runtime.h>
#include <cstdint>
#include <cstddef>

#define B_  1024
#define T_  100
#define H_  256

typedef _Float16 f16x8 __attribute__((ext_vector_type(8)));
typedef float    f32x16 __attribute__((ext_vector_type(16)));

__device__ __forceinline__ float sigm(float x){ return 1.0f/(1.0f + __expf(-x)); }
__device__ __forceinline__ float tanh_(float x){ return 1.0f - 2.0f/(1.0f + __expf(2.0f*x)); }

// fp16 weight pool offsets (elements)
#define W_WHH1F 0
#define W_WHH1B 262144
#define W_WIH2F 524288
#define W_WIH2B 1048576
#define W_WHH2F 1572864
#define W_WHH2B 1835008
#define W_TOTAL 2097152

// Stage a 64-row x 256-col fp16 A-chunk into LDS, run 16 K-steps of
// v_mfma_f32_32x32x16_f16 for the 4 gate column-groups.
// A-operand: lane holds A[m=lane&31][k=(lane>>5)*8 + j]
// B-operand: lane holds W[n=lane&31 (+base)][k=(lane>>5)*8 + j]
// C/D:       col = lane&31, row = (reg&3) + 8*(reg>>2) + 4*(lane>>5)
__device__ __forceinline__ void gemm_chunk(
    f32x16 acc[4],
    const _Float16* __restrict__ Asrc, int a_stride,
    const _Float16* __restrict__ Wsrc, int w_stride,
    _Float16* Alds,                               // [64][264]
    int b0, int j0, int lane, int rw, int cw)
{
  const int t = threadIdx.x;
  #pragma unroll
  for (int i = 0; i < 8; i++){
    int u   = t + 256*i;
    int row = u >> 5;      // 0..63
    int c8  = u & 31;      // 16B unit within row
    uint4 v = *(const uint4*)(Asrc + (size_t)(b0 + row)*a_stride + c8*8);
    *(uint4*)(Alds + row*264 + c8*8) = v;
  }
  __syncthreads();
  const _Float16* arow = Alds + (rw*32 + (lane & 31))*264 + (lane >> 5)*8;
  const int nbase = j0 + cw*32 + (lane & 31);
  const int kq    = (lane >> 5)*8;
  #pragma unroll
  for (int kk = 0; kk < 16; kk++){
    f16x8 a = *(const f16x8*)(arow + kk*16);
    #pragma unroll
    for (int g = 0; g < 4; g++){
      const _Float16* wp = Wsrc + (size_t)(g*256 + nbase)*w_stride + kk*16 + kq;
      f16x8 bw = *(const f16x8*)wp;
      acc[g] = __builtin_amdgcn_mfma_f32_32x32x16_f16(a, bw, acc[g], 0, 0, 0);
    }
  }
  __syncthreads();
}

__global__ void conv_weights(const float* __restrict__ Whh1f, const float* __restrict__ Whh1b,
                             const float* __restrict__ Wih2f, const float* __restrict__ Wih2b,
                             const float* __restrict__ Whh2f, const float* __restrict__ Whh2b,
                             _Float16* __restrict__ dst)
{
  int idx = blockIdx.x*256 + threadIdx.x;
  if      (idx < W_WHH1B) dst[idx] = (_Float16)Whh1f[idx];
  else if (idx < W_WIH2F) dst[idx] = (_Float16)Whh1b[idx - W_WHH1B];
  else if (idx < W_WIH2B) dst[idx] = (_Float16)Wih2f[idx - W_WIH2F];
  else if (idx < W_WHH2F) dst[idx] = (_Float16)Wih2b[idx - W_WIH2B];
  else if (idx < W_WHH2B) dst[idx] = (_Float16)Whh2f[idx - W_WHH2F];
  else if (idx < W_TOTAL) dst[idx] = (_Float16)Whh2b[idx - W_WHH2B];
}

__global__ __launch_bounds__(256, 2)
void l1_step(const _Float16* __restrict__ wpool,
             const float* __restrict__ Wih_f,
             const float* __restrict__ Wih_b,
             const float* __restrict__ bih_f,
             const float* __restrict__ bhh_f,
             const float* __restrict__ bih_b,
             const float* __restrict__ bhh_b,
             const float* __restrict__ x0,
             const float* __restrict__ mvec,
             const float* __restrict__ mask1,
             const float* __restrict__ mask2,
             const _Float16* __restrict__ hm_in,
             _Float16* __restrict__ hm_out,
             float* __restrict__ cbuf,
             _Float16* __restrict__ p1m,
             int s)
{
  __shared__ __align__(16) _Float16 Alds[64*264];
  const int dir = blockIdx.z;
  const int b0  = blockIdx.x*64, j0 = blockIdx.y*64;
  const int lane = threadIdx.x & 63;
  const int w = threadIdx.x >> 6, rw = w >> 1, cw = w & 1;

  f32x16 acc[4];
  #pragma unroll
  for (int g = 0; g < 4; g++)
    #pragma unroll
    for (int e = 0; e < 16; e++) acc[g][e] = 0.0f;

  const _Float16* Whh = wpool + (dir ? W_WHH1B : W_WHH1F);
  gemm_chunk(acc, hm_in + (size_t)dir*B_*H_, H_, Whh, H_, Alds, b0, j0, lane, rw, cw);

  const int tin = dir ? (T_-1-s) : s;
  const float* Wih = dir ? Wih_b : Wih_f;
  const float* bih = dir ? bih_b : bih_f;
  const float* bhh = dir ? bhh_b : bhh_f;
  const int jj = j0 + cw*32 + (lane & 31);

  float wi0[4], wi1[4], bs[4];
  #pragma unroll
  for (int g = 0; g < 4; g++){
    int n = g*256 + jj;
    wi0[g] = Wih[n*2 + 0];
    wi1[g] = Wih[n*2 + 1];
    bs[g]  = bih[n] + bhh[n];
  }
  float* cp = cbuf + (size_t)dir*B_*H_;
  _Float16* hmo = hm_out + (size_t)dir*B_*H_;

  #pragma unroll
  for (int r = 0; r < 16; r++){
    int row = (r & 3) + 8*(r >> 2) + 4*(lane >> 5);
    int b   = b0 + rw*32 + row;
    float mv = mvec[b];
    float xd = x0[b*T_ + tin] - mv;
    float gi = acc[0][r] + xd*wi0[0] + mv*wi1[0] + bs[0];
    float gf = acc[1][r] + xd*wi0[1] + mv*wi1[1] + bs[1];
    float gg = acc[2][r] + xd*wi0[2] + mv*wi1[2] + bs[2];
    float go = acc[3][r] + xd*wi0[3] + mv*wi1[3] + bs[3];
    float ii = sigm(gi), ff = sigm(gf), g2 = tanh_(gg), oo = sigm(go);
    size_t cidx = (size_t)b*H_ + jj;
    float cn = ff*cp[cidx] + ii*g2;
    cp[cidx] = cn;
    float h = oo*tanh_(cn);
    hmo[cidx] = (_Float16)(h * mask1[cidx]);
    p1m[((size_t)s*B_ + b)*512 + dir*256 + jj] =
        (_Float16)(h * mask2[(size_t)b*512 + dir*256 + jj]);
  }
}

__global__ __launch_bounds__(256, 2)
void l2_step(const _Float16* __restrict__ wpool,
             const float* __restrict__ bih_f,
             const float* __restrict__ bhh_f,
             const float* __restrict__ bih_b,
             const float* __restrict__ bhh_b,
             const _Float16* __restrict__ p1m,
             const float* __restrict__ mask3,
             const float* __restrict__ mask4,
             const float* __restrict__ Wout,
             const _Float16* __restrict__ hm_in,
             _Float16* __restrict__ hm_out,
             float* __restrict__ cbuf,
             float* __restrict__ pred,
             int s)
{
  __shared__ __align__(16) _Float16 Alds[64*264];
  const int dir = blockIdx.z;
  const int b0  = blockIdx.x*64, j0 = blockIdx.y*64;
  const int lane = threadIdx.x & 63;
  const int w = threadIdx.x >> 6, rw = w >> 1, cw = w & 1;

  f32x16 acc[4];
  #pragma unroll
  for (int g = 0; g < 4; g++)
    #pragma unroll
    for (int e = 0; e < 16; e++) acc[g][e] = 0.0f;

  const int tin = dir ? (T_-1-s) : s;
  const _Float16* Wih = wpool + (dir ? W_WIH2B : W_WIH2F);
  const _Float16* Whh = wpool + (dir ? W_WHH2B : W_WHH2F);
  const _Float16* Ain = p1m + (size_t)tin*B_*512;

  gemm_chunk(acc, Ain,       512, Wih,       512, Alds, b0, j0, lane, rw, cw);
  gemm_chunk(acc, Ain + 256, 512, Wih + 256, 512, Alds, b0, j0, lane, rw, cw);
  gemm_chunk(acc, hm_in + (size_t)dir*B_*H_, H_, Whh, H_, Alds, b0, j0, lane, rw, cw);

  const float* bih = dir ? bih_b : bih_f;
  const float* bhh = dir ? bhh_b : bhh_f;
  const int jj = j0 + cw*32 + (lane & 31);
  float bs[4];
  #pragma unroll
  for (int g = 0; g < 4; g++)
    bs[g] = bih[g*256 + jj] + bhh[g*256 + jj];
  float wo = Wout[dir*256 + jj];
  float* cp = cbuf + (size_t)dir*B_*H_;
  _Float16* hmo = hm_out + (size_t)dir*B_*H_;

  #pragma unroll
  for (int r = 0; r < 16; r++){
    int row = (r & 3) + 8*(r >> 2) + 4*(lane >> 5);
    int b   = b0 + rw*32 + row;
    float gi = acc[0][r] + bs[0];
    float gf = acc[1][r] + bs[1];
    float gg = acc[2][r] + bs[2];
    float go = acc[3][r] + bs[3];
    float ii = sigm(gi), ff = sigm(gf), g2 = tanh_(gg), oo = sigm(go);
    size_t cidx = (size_t)b*H_ + jj;
    float cn = ff*cp[cidx] + ii*g2;
    cp[cidx] = cn;
    float h = oo*tanh_(cn);
    hmo[cidx] = (_Float16)(h * mask3[cidx]);
    float contrib = h * mask4[(size_t)b*512 + dir*256 + jj] * wo;
    contrib += __shfl_xor(contrib, 16);
    contrib += __shfl_xor(contrib, 8);
    contrib += __shfl_xor(contrib, 4);
    contrib += __shfl_xor(contrib, 2);
    contrib += __shfl_xor(contrib, 1);
    if ((lane & 31) == 0) atomicAdd(&pred[(size_t)b*T_ + s], contrib);
  }
}

__global__ void prep_kernel(const float* __restrict__ x0,
                            float* __restrict__ mvec)
{
  int b = blockIdx.x*blockDim.x + threadIdx.x;
  if (b < B_){
    float ssum = 0.0f;
    for (int t = 0; t < T_; t++) ssum += x0[b*T_ + t];
    mvec[b] = ssum * (1.0f / T_);
  }
}

__global__ void final_kernel(const float* __restrict__ pred,
                             const float* __restrict__ mvec,
                             const float* __restrict__ bout,
                             float* __restrict__ out)
{
  int idx = blockIdx.x*256 + threadIdx.x;
  if (idx < B_*T_){
    int b = idx / T_;
    out[idx] = pred[idx] + bout[0] + mvec[b];
  }
}

extern "C" void kernel_launch(void* const* d_in, const int* in_sizes, int n_in,
                              void* d_out, int out_size, void* d_ws, size_t ws_size,
                              hipStream_t stream)
{
  (void)in_sizes; (void)n_in; (void)out_size; (void)ws_size;
  const float* x0    = (const float*)d_in[0];
  const float* Wih1f = (const float*)d_in[1];
  const float* Whh1f = (const float*)d_in[2];
  const float* bih1f = (const float*)d_in[3];
  const float* bhh1f = (const float*)d_in[4];
  const float* Wih1b = (const float*)d_in[5];
  const float* Whh1b = (const float*)d_in[6];
  const float* bih1b = (const float*)d_in[7];
  const float* bhh1b = (const float*)d_in[8];
  const float* Wih2f = (const float*)d_in[9];
  const float* Whh2f = (const float*)d_in[10];
  const float* bih2f = (const float*)d_in[11];
  const float* bhh2f = (const float*)d_in[12];
  const float* Wih2b = (const float*)d_in[13];
  const float* Whh2b = (const float*)d_in[14];
  const float* bih2b = (const float*)d_in[15];
  const float* bhh2b = (const float*)d_in[16];
  const float* Wout  = (const float*)d_in[17];
  const float* bout  = (const float*)d_in[18];
  const float* mask1 = (const float*)d_in[19];
  const float* mask2 = (const float*)d_in[20];
  const float* mask3 = (const float*)d_in[21];
  const float* mask4 = (const float*)d_in[22];
  float* out = (float*)d_out;

  // Workspace layout (~118 MB)
  char* ws = (char*)d_ws;
  size_t off = 0;
  _Float16* wpool = (_Float16*)(ws + off); off += (size_t)W_TOTAL*2;               // 4.2 MB
  _Float16* p1m  = (_Float16*)(ws + off); off += (size_t)T_*B_*512*2;              // 104.8 MB
  float* pred = (float*)(ws + off); off += (size_t)B_*T_*4;                        // 0.4 MB
  float* mvec = (float*)(ws + off); off += (size_t)B_*4;
  float* cbuf = (float*)(ws + off); off += (size_t)2*2*B_*H_*4;                    // 4 MB
  _Float16* hm = (_Float16*)(ws + off); off += (size_t)2*2*2*B_*H_*2;              // 4 MB

  hipMemsetAsync(pred, 0, (size_t)B_*T_*4, stream);
  hipMemsetAsync(cbuf, 0, (size_t)2*2*B_*H_*4 + (size_t)2*2*2*B_*H_*2, stream);

  conv_weights<<<dim3(W_TOTAL/256), dim3(256), 0, stream>>>(
      Whh1f, Whh1b, Wih2f, Wih2b, Whh2f, Whh2b, wpool);
  prep_kernel<<<dim3(4), dim3(256), 0, stream>>>(x0, mvec);

  dim3 grid(16, 4, 2), blk(256);
  float* cL1 = cbuf;
  float* cL2 = cbuf + (size_t)2*B_*H_;
  _Float16* hmL1 = hm;
  _Float16* hmL2 = hm + (size_t)2*2*B_*H_;
  const size_t pp = (size_t)2*B_*H_;

  for (int s = 0; s < T_; s++){
    l1_step<<<grid, blk, 0, stream>>>(wpool, Wih1f, Wih1b,
        bih1f, bhh1f, bih1b, bhh1b, x0, mvec, mask1, mask2,
        hmL1 + (size_t)(s & 1)*pp, hmL1 + (size_t)((s + 1) & 1)*pp, cL1, p1m, s);
  }
  for (int s = 0; s < T_; s++){
    l2_step<<<grid, blk, 0, stream>>>(wpool,
        bih2f, bhh2f, bih2b, bhh2b, p1m, mask3, mask4, Wout,
        hmL2 + (size_t)(s & 1)*pp, hmL2 + (size_t)((s + 1) & 1)*pp, cL2, pred, s);
  }
  final_kernel<<<dim3((B_*T_ + 255)/256), dim3(256), 0, stream>>>(pred, mvec, bout, out);
}